// Round 4
// baseline (154.029 us; speedup 1.0000x reference)
//
#include <hip/hip_runtime.h>
#include <hip/hip_bf16.h>

typedef __attribute__((ext_vector_type(8))) short bf16x8;
typedef __attribute__((ext_vector_type(4))) float f32x4;

// exp(v/T - 5) with T=0.2  ==  exp2( (v-1) * 5*log2(e) )
#define EXP_SCALE 7.213475204444817f

__device__ __forceinline__ float fast_exp2(float x) {
#if __has_builtin(__builtin_amdgcn_exp2f)
  return __builtin_amdgcn_exp2f(x);
#else
  return exp2f(x);
#endif
}

__device__ __forceinline__ unsigned short f32_to_bf16(float f) {
  unsigned int u = __float_as_uint(f);
  unsigned int r = (u + 0x7FFFu + ((u >> 16) & 1u)) >> 16;
  return (unsigned short)r;
}

// z is stored SWIZZLED in MFMA-fragment order:
//   shorts addr = tile*2048 + kk*512 + slot*8 + rem
// where tile = row>>4, c = row&15, element e: kk = e>>5, q = (e>>3)&3,
// rem = e&7, slot = q*16 + c. A wave (lane = q*16+c) then loads one
// (tile,kk) fragment as one contiguous 1KB global_load_dwordx4 at
// z + tile*2048 + kk*512 + lane*8.

// Kernel 1: L2-normalize rows -> swizzled bf16 z. Also zeroes the
// completion counter used by k_simlse's fused finish.
__global__ __launch_bounds__(256) void k_normalize(
    const float* __restrict__ emb_i, const float* __restrict__ emb_j,
    unsigned short* __restrict__ z, unsigned int* __restrict__ counter)
{
  if (blockIdx.x == 0 && threadIdx.x == 0) counter[0] = 0u;
  const int w = threadIdx.x >> 6;
  const int lane = threadIdx.x & 63;
  const int row = (blockIdx.x << 2) + w;
  const float* src = (row < 4096) ? (emb_i + row * 128) : (emb_j + (row - 4096) * 128);
  float2 v = reinterpret_cast<const float2*>(src)[lane];
  float ss = v.x * v.x + v.y * v.y;
  #pragma unroll
  for (int m = 1; m < 64; m <<= 1) ss += __shfl_xor(ss, m, 64);
  float rinv = 1.0f / sqrtf(ss);
  ushort2 st;
  st.x = f32_to_bf16(v.x * rinv);
  st.y = f32_to_bf16(v.y * rinv);
  const int e = lane << 1;
  const int kk = e >> 5;
  const int q = (e >> 3) & 3;
  const int rem = e & 7;
  const int tile = row >> 4;
  const int c = row & 15;
  unsigned short* dst = z + tile * 2048 + kk * 512 + ((q << 4) + c) * 8 + rem;
  *reinterpret_cast<ushort2*>(dst) = st;
}

// Kernel 2: block = 64 rows x 1024-col chunk; 4 waves each own all 64 rows
// (A in regs, 16 bf16x8) and walk 16 col-tiles (stride 4 tiles). Ping-pong
// register double-buffer (all indices compile-time -> no scratch). Diagonal
// exp term (==1 for unit rows) is kept; finish subtracts 1.
// Last block to finish does the log/mean reduction and writes out[0].
__global__ __launch_bounds__(256, 3) void k_simlse(
    const unsigned short* __restrict__ z,
    float* __restrict__ rowsum,   // [8][8192]
    float* __restrict__ rowpos,   // [8192]
    unsigned int* __restrict__ counter,
    float* __restrict__ out)
{
  const int w = threadIdx.x >> 6;
  const int lane = threadIdx.x & 63;
  const int q = lane >> 4;
  const int c = lane & 15;
  const int rb = blockIdx.x >> 3;       // 0..127
  const int ch = blockIdx.x & 7;        // 0..7
  const int R0 = rb << 6;               // 64-row block

  // A fragments: tiles R0/16 .. R0/16+3, each kk 0..3; contiguous 1KB loads
  bf16x8 a[4][4];
  {
    const unsigned short* ap = z + (R0 >> 4) * 2048 + (lane << 3);
    #pragma unroll
    for (int rg = 0; rg < 4; ++rg)
      #pragma unroll
      for (int kk = 0; kk < 4; ++kk)
        a[rg][kk] = *reinterpret_cast<const bf16x8*>(ap + rg * 2048 + kk * 512);
  }

  float acc[4][4];
  #pragma unroll
  for (int rg = 0; rg < 4; ++rg)
    #pragma unroll
    for (int e = 0; e < 4; ++e) acc[rg][e] = 0.0f;
  float pacc[4] = {0.f, 0.f, 0.f, 0.f};

  const int ct0 = (ch << 6) + w;                  // first 16-col tile
  const int pos0 = ((R0 + 4096) & 8191) >> 4;     // pos tile for rg is pos0+rg
  const int i_pos = ((pos0 >> 6) == ch) ? ((pos0 - (ch << 6)) >> 2) : -1;

  const unsigned short* bwave = z + ct0 * 2048 + (lane << 3);
  // wave's tile stride = 4 tiles = 8192 shorts

  bf16x8 b0[4], b1[4];

  auto ldb = [&](bf16x8 (&dst)[4], int idx) {
    const unsigned short* p = bwave + idx * 8192;
    dst[0] = *reinterpret_cast<const bf16x8*>(p);
    dst[1] = *reinterpret_cast<const bf16x8*>(p + 512);
    dst[2] = *reinterpret_cast<const bf16x8*>(p + 1024);
    dst[3] = *reinterpret_cast<const bf16x8*>(p + 1536);
  };

  auto process = [&](const bf16x8 (&bb)[4], int i) {
    f32x4 cc[4];
    #pragma unroll
    for (int rg = 0; rg < 4; ++rg) cc[rg] = f32x4{0.f, 0.f, 0.f, 0.f};
    #pragma unroll
    for (int kk = 0; kk < 4; ++kk)
      #pragma unroll
      for (int rg = 0; rg < 4; ++rg)
        cc[rg] = __builtin_amdgcn_mfma_f32_16x16x32_bf16(a[rg][kk], bb[kk], cc[rg], 0, 0, 0);
    #pragma unroll
    for (int rg = 0; rg < 4; ++rg)
      #pragma unroll
      for (int e = 0; e < 4; ++e)
        acc[rg][e] += fast_exp2(__builtin_fmaf(cc[rg][e], EXP_SCALE, -EXP_SCALE));
    if (i == i_pos) {   // rare, wave-uniform
      #pragma unroll
      for (int rg = 0; rg < 4; ++rg) {
        if (w == rg) {
          #pragma unroll
          for (int e = 0; e < 4; ++e)
            if (c == ((q << 2) + e)) pacc[e] = cc[rg][e] * 5.0f;
        }
      }
    }
  };

  ldb(b0, 0);
  #pragma unroll 1
  for (int i = 0; i < 16; i += 2) {
    ldb(b1, i + 1);
    process(b0, i);
    if (i + 2 < 16) ldb(b0, i + 2);
    process(b1, i + 1);
  }

  // Reduce over the 16 cols (c-group: xor masks 1,2,4,8)
  #pragma unroll
  for (int m = 1; m < 16; m <<= 1) {
    #pragma unroll
    for (int rg = 0; rg < 4; ++rg)
      #pragma unroll
      for (int e = 0; e < 4; ++e)
        acc[rg][e] += __shfl_xor(acc[rg][e], m, 64);
    #pragma unroll
    for (int e = 0; e < 4; ++e) pacc[e] += __shfl_xor(pacc[e], m, 64);
  }

  __shared__ float lsum[4][64];
  __shared__ float lpos[4][16];
  if (c == 0) {
    #pragma unroll
    for (int rg = 0; rg < 4; ++rg)
      #pragma unroll
      for (int e = 0; e < 4; ++e)
        lsum[w][(rg << 4) + (q << 2) + e] = acc[rg][e];
    #pragma unroll
    for (int e = 0; e < 4; ++e) lpos[w][(q << 2) + e] = pacc[e];
  }
  __syncthreads();
  if (threadIdx.x < 64) {
    const int t = threadIdx.x;
    const int r = R0 + t;
    float s = lsum[0][t] + lsum[1][t] + lsum[2][t] + lsum[3][t];
    rowsum[(ch << 13) + r] = s;
    const int P = (R0 + 4096) & 8191;
    if (ch == (P >> 10))                 // this chunk owns the positive cols
      rowpos[r] = lpos[t >> 4][t & 15];
  }

  // ---- fused finish: last block computes the loss ----
  __shared__ unsigned int s_last;
  __threadfence();                       // make rowsum/rowpos visible (device scope)
  __syncthreads();
  if (threadIdx.x == 0)
    s_last = (atomicAdd(counter, 1u) == gridDim.x - 1) ? 1u : 0u;
  __syncthreads();
  if (s_last) {
    __threadfence();                     // acquire: invalidate stale cache lines
    float s = 0.0f;
    for (int j = 0; j < 32; ++j) {
      const int r = (j << 8) + threadIdx.x;
      float tot = -1.0f;                 // remove diagonal exp term (==1)
      #pragma unroll
      for (int chunk = 0; chunk < 8; ++chunk) tot += rowsum[(chunk << 13) + r];
      s += 5.0f + logf(tot) - rowpos[r];
    }
    #pragma unroll
    for (int m = 1; m < 64; m <<= 1) s += __shfl_xor(s, m, 64);
    __shared__ float red[4];
    if ((threadIdx.x & 63) == 0) red[threadIdx.x >> 6] = s;
    __syncthreads();
    if (threadIdx.x == 0)
      out[0] = (red[0] + red[1] + red[2] + red[3]) * (1.0f / 8192.0f);
  }
}

extern "C" void kernel_launch(void* const* d_in, const int* in_sizes, int n_in,
                              void* d_out, int out_size, void* d_ws, size_t ws_size,
                              hipStream_t stream) {
  const float* emb_i = (const float*)d_in[0];
  const float* emb_j = (const float*)d_in[1];
  unsigned short* z = (unsigned short*)d_ws;                       // 2 MB (swizzled)
  float* rowsum = (float*)((char*)d_ws + 8192 * 128 * 2);          // [8][8192] = 256 KB
  float* rowpos = rowsum + 8 * 8192;                               // [8192] = 32 KB
  unsigned int* counter = (unsigned int*)(rowpos + 8192);          // 4 B
  float* out = (float*)d_out;

  k_normalize<<<2048, 256, 0, stream>>>(emb_i, emb_j, z, counter);
  k_simlse<<<1024, 256, 0, stream>>>(z, rowsum, rowpos, counter, out);
}

// Round 5
// 88.640 us; speedup vs baseline: 1.7377x; 1.7377x over previous
//
#include <hip/hip_runtime.h>
#include <hip/hip_bf16.h>

typedef __attribute__((ext_vector_type(8))) short bf16x8;
typedef __attribute__((ext_vector_type(4))) float f32x4;

// exp(v/T - 5) with T=0.2  ==  exp2( (v-1) * 5*log2(e) )
#define EXP_SCALE 7.213475204444817f

__device__ __forceinline__ float fast_exp2(float x) {
#if __has_builtin(__builtin_amdgcn_exp2f)
  return __builtin_amdgcn_exp2f(x);
#else
  return exp2f(x);
#endif
}

__device__ __forceinline__ unsigned short f32_to_bf16(float f) {
  unsigned int u = __float_as_uint(f);
  unsigned int r = (u + 0x7FFFu + ((u >> 16) & 1u)) >> 16;
  return (unsigned short)r;
}

// z is stored SWIZZLED in MFMA-fragment order:
//   shorts addr = tile*2048 + kk*512 + slot*8 + rem
// where tile = row>>4, c = row&15, element e: kk = e>>5, q = (e>>3)&3,
// rem = e&7, slot = q*16 + c. A wave (lane = q*16+c) loads one (tile,kk)
// fragment as one contiguous 1KB global_load_dwordx4 at
// z + tile*2048 + kk*512 + lane*8.

// Kernel 1: L2-normalize rows -> swizzled bf16 z. Zeroes out[0] for
// k_finish's atomicAdd (harness poisons d_out before every launch).
__global__ __launch_bounds__(256) void k_normalize(
    const float* __restrict__ emb_i, const float* __restrict__ emb_j,
    unsigned short* __restrict__ z, float* __restrict__ out)
{
  if (blockIdx.x == 0 && threadIdx.x == 0) out[0] = 0.0f;
  const int w = threadIdx.x >> 6;
  const int lane = threadIdx.x & 63;
  const int row = (blockIdx.x << 2) + w;
  const float* src = (row < 4096) ? (emb_i + row * 128) : (emb_j + (row - 4096) * 128);
  float2 v = reinterpret_cast<const float2*>(src)[lane];
  float ss = v.x * v.x + v.y * v.y;
  #pragma unroll
  for (int m = 1; m < 64; m <<= 1) ss += __shfl_xor(ss, m, 64);
  float rinv = 1.0f / sqrtf(ss);
  ushort2 st;
  st.x = f32_to_bf16(v.x * rinv);
  st.y = f32_to_bf16(v.y * rinv);
  const int e = lane << 1;
  const int kk = e >> 5;
  const int q = (e >> 3) & 3;
  const int rem = e & 7;
  const int tile = row >> 4;
  const int c = row & 15;
  unsigned short* dst = z + tile * 2048 + kk * 512 + ((q << 4) + c) * 8 + rem;
  *reinterpret_cast<ushort2*>(dst) = st;
}

// Kernel 2: block = 128 rows x 1024-col chunk. A (128 rows, 32KB) staged
// once via LDS then held in registers a[8][4]; 4 waves each stream their own
// B col-tiles (stride 4 tiles, 16 iters, ping-pong double buffer). 32 MFMAs
// per 4KB of B (2x the arithmetic intensity of the 64-row version).
// Diagonal exp term (==1 for unit rows) kept; k_finish subtracts 1.
__global__ __launch_bounds__(256, 2) void k_simlse(
    const unsigned short* __restrict__ z,
    float* __restrict__ rowsum,   // [8][8192]
    float* __restrict__ rowpos)   // [8192]
{
  const int w = threadIdx.x >> 6;
  const int lane = threadIdx.x & 63;
  const int q = lane >> 4;
  const int c = lane & 15;
  const int rb = blockIdx.x >> 3;       // 0..63
  const int ch = blockIdx.x & 7;        // 0..7
  const int R0 = rb << 7;               // 128-row block

  // ---- stage A (tiles T0..T0+7, 32KB) into LDS, then into registers ----
  __shared__ short smem[16384];         // 32KB
  {
    const unsigned short* zA = z + (R0 >> 4) * 2048;
    #pragma unroll
    for (int j = 0; j < 8; ++j) {
      const int v = (j << 8) + threadIdx.x;   // 0..2047 vec8 chunks
      *reinterpret_cast<bf16x8*>(&smem[v << 3]) =
          *reinterpret_cast<const bf16x8*>(zA + (v << 3));
    }
  }
  __syncthreads();
  bf16x8 a[8][4];
  #pragma unroll
  for (int rg = 0; rg < 8; ++rg)
    #pragma unroll
    for (int kk = 0; kk < 4; ++kk)
      a[rg][kk] = *reinterpret_cast<const bf16x8*>(
          &smem[rg * 2048 + kk * 512 + (lane << 3)]);

  float acc[8][4];
  #pragma unroll
  for (int rg = 0; rg < 8; ++rg)
    #pragma unroll
    for (int e = 0; e < 4; ++e) acc[rg][e] = 0.0f;
  float pacc[2][4] = {{0.f,0.f,0.f,0.f},{0.f,0.f,0.f,0.f}};

  const int ct0 = (ch << 6) + w;                  // first 16-col tile
  const int pos0 = ((R0 + 4096) & 8191) >> 4;     // 8-aligned pos tile base
  // wave w owns pos tiles pos0+w (at i=ipb) and pos0+w+4 (at i=ipb+1)
  const int ipb = ((pos0 >> 6) == ch) ? ((pos0 & 63) >> 2) : -99;

  const unsigned short* bwave = z + ct0 * 2048 + (lane << 3);

  bf16x8 b0[4], b1[4];
  auto ldb = [&](bf16x8 (&dst)[4], int idx) {
    const unsigned short* p = bwave + idx * 8192;   // stride 4 tiles
    dst[0] = *reinterpret_cast<const bf16x8*>(p);
    dst[1] = *reinterpret_cast<const bf16x8*>(p + 512);
    dst[2] = *reinterpret_cast<const bf16x8*>(p + 1024);
    dst[3] = *reinterpret_cast<const bf16x8*>(p + 1536);
  };

  auto process = [&](const bf16x8 (&bb)[4], int i) {
    #pragma unroll
    for (int hb = 0; hb < 2; ++hb) {                // two rg-halves: peak regs down
      f32x4 cc[4];
      #pragma unroll
      for (int rr = 0; rr < 4; ++rr) cc[rr] = f32x4{0.f, 0.f, 0.f, 0.f};
      #pragma unroll
      for (int kk = 0; kk < 4; ++kk)
        #pragma unroll
        for (int rr = 0; rr < 4; ++rr)
          cc[rr] = __builtin_amdgcn_mfma_f32_16x16x32_bf16(
              a[(hb << 2) + rr][kk], bb[kk], cc[rr], 0, 0, 0);
      #pragma unroll
      for (int rr = 0; rr < 4; ++rr)
        #pragma unroll
        for (int e = 0; e < 4; ++e)
          acc[(hb << 2) + rr][e] +=
              fast_exp2(__builtin_fmaf(cc[rr][e], EXP_SCALE, -EXP_SCALE));
      if (i == ipb + hb) {               // rare, wave-uniform
        #pragma unroll
        for (int rr = 0; rr < 4; ++rr) {
          if (rr == w) {
            #pragma unroll
            for (int e = 0; e < 4; ++e)
              if (c == ((q << 2) + e)) pacc[hb][e] = cc[rr][e] * 5.0f;
          }
        }
      }
    }
  };

  ldb(b0, 0);
  #pragma unroll 1
  for (int i = 0; i < 16; i += 2) {
    ldb(b1, i + 1);
    process(b0, i);
    if (i + 2 < 16) ldb(b0, i + 2);
    process(b1, i + 1);
  }

  // Reduce over the 16 cols (c-group: xor masks 1,2,4,8)
  #pragma unroll
  for (int m = 1; m < 16; m <<= 1) {
    #pragma unroll
    for (int rg = 0; rg < 8; ++rg)
      #pragma unroll
      for (int e = 0; e < 4; ++e)
        acc[rg][e] += __shfl_xor(acc[rg][e], m, 64);
    #pragma unroll
    for (int hb = 0; hb < 2; ++hb)
      #pragma unroll
      for (int e = 0; e < 4; ++e)
        pacc[hb][e] += __shfl_xor(pacc[hb][e], m, 64);
  }

  __shared__ float lsum[4 * 128];
  __shared__ float lpos[4 * 32];
  __syncthreads();                       // smem A-staging no longer needed
  if (c == 0) {
    #pragma unroll
    for (int rg = 0; rg < 8; ++rg)
      #pragma unroll
      for (int e = 0; e < 4; ++e)
        lsum[w * 128 + rg * 16 + (q << 2) + e] = acc[rg][e];
    #pragma unroll
    for (int hb = 0; hb < 2; ++hb)
      #pragma unroll
      for (int e = 0; e < 4; ++e)
        lpos[w * 32 + hb * 16 + (q << 2) + e] = pacc[hb][e];
  }
  __syncthreads();
  if (threadIdx.x < 128) {
    const int t = threadIdx.x;
    const int r = R0 + t;
    float s = lsum[t] + lsum[128 + t] + lsum[256 + t] + lsum[384 + t];
    rowsum[(ch << 13) + r] = s;
    if (ch == (pos0 >> 6)) {             // this chunk owns the positive cols
      const int rg = t >> 4;
      rowpos[r] = lpos[(rg & 3) * 32 + (rg >> 2) * 16 + (t & 15)];
    }
  }
}

// Kernel 3: tot = sum over 8 chunks minus diagonal term (==1);
// lse = 5 + log(tot); loss = mean(lse - pos). atomicAdd into out (zeroed
// by k_normalize; same-stream ordering guarantees visibility).
__global__ __launch_bounds__(256) void k_finish(
    const float* __restrict__ rowsum, const float* __restrict__ rowpos,
    float* __restrict__ out)
{
  const int r = blockIdx.x * 256 + threadIdx.x;
  float tot = -1.0f;
  #pragma unroll
  for (int chunk = 0; chunk < 8; ++chunk) tot += rowsum[(chunk << 13) + r];
  float v = 5.0f + logf(tot) - rowpos[r];
  #pragma unroll
  for (int m = 1; m < 64; m <<= 1) v += __shfl_xor(v, m, 64);
  __shared__ float red[4];
  if ((threadIdx.x & 63) == 0) red[threadIdx.x >> 6] = v;
  __syncthreads();
  if (threadIdx.x == 0)
    atomicAdd(out, (red[0] + red[1] + red[2] + red[3]) * (1.0f / 8192.0f));
}

extern "C" void kernel_launch(void* const* d_in, const int* in_sizes, int n_in,
                              void* d_out, int out_size, void* d_ws, size_t ws_size,
                              hipStream_t stream) {
  const float* emb_i = (const float*)d_in[0];
  const float* emb_j = (const float*)d_in[1];
  unsigned short* z = (unsigned short*)d_ws;                       // 2 MB (swizzled)
  float* rowsum = (float*)((char*)d_ws + 8192 * 128 * 2);          // [8][8192] = 256 KB
  float* rowpos = rowsum + 8 * 8192;                               // [8192] = 32 KB
  float* out = (float*)d_out;

  k_normalize<<<2048, 256, 0, stream>>>(emb_i, emb_j, z, out);
  k_simlse<<<512, 256, 0, stream>>>(z, rowsum, rowpos);
  k_finish<<<32, 256, 0, stream>>>(rowsum, rowpos, out);
}